// Round 12
// baseline (15370.074 us; speedup 1.0000x reference)
//
#include <hip/hip_runtime.h>
#include <math.h>

#define NN 1600
#define MAXD 500
#define TS 500
#define NBATCH 4
#define GBLK 100
#define WAVES 4
#define NWAVE (GBLK * WAVES)   // 400 waves
#define RPW 4                  // rows per wave; 400*4 = 1600
#define NFLAG 512              // u16 slots; >= NWAVE preset to 0xFFFF (always pass)
#define DT 0.05f

typedef unsigned int u32;
typedef unsigned short u16;

// ---------------- workspace layout (floats) ----------------
// cnt   : [0      , 800000)   N*MAXD delay-count weights
// Hc    : [800000 , 1600000)  circular history, head h (logical d -> (h+d)%MAXD)
// deT   : [1600000, 1603200)  double-buffered delayed_E (2 * N), plain floats
// flags : float offset 1603200, NFLAG u16 dense (1 KB: one dwordx4/lane covers all)

#define ATSF(p,v)   __hip_atomic_store((p), (v), __ATOMIC_RELAXED, __HIP_MEMORY_SCOPE_AGENT)
#define ATSU(p,v)   __hip_atomic_store((p), (v), __ATOMIC_RELAXED, __HIP_MEMORY_SCOPE_AGENT)
#define ATSU16(p,v) __hip_atomic_store((p), (v), __ATOMIC_RELAXED, __HIP_MEMORY_SCOPE_AGENT)

__device__ __forceinline__ float h_tf_dev(float a, float b, float d, float c) {
    float u   = a * c - b;
    float num = 1e-5f + fabsf(u);
    float den = 1e-5f * d + fabsf(1.0f - expf(-d * u));
    return num / (den + 1e-8f);
}

__global__ void cnt_kernel(const int* __restrict__ delays, float* __restrict__ cnt) {
    __shared__ int hist[MAXD];
    const int i = blockIdx.x;
    for (int d = threadIdx.x; d < MAXD; d += blockDim.x) hist[d] = 0;
    __syncthreads();
    const int* row = delays + (size_t)i * NN;
    for (int j = threadIdx.x; j < NN; j += blockDim.x) atomicAdd(&hist[row[j]], 1);
    __syncthreads();
    for (int d = threadIdx.x; d < MAXD; d += blockDim.x)
        cnt[(size_t)i * MAXD + d] = (float)hist[d];
}

__global__ void init_kernel(const float* __restrict__ hE, const float* __restrict__ cnt,
                            float* __restrict__ Hc, float* deT, u32* flags32) {
    const int i = blockIdx.x;     // one wave per row
    const int lane = threadIdx.x; // 64 threads
    float s = 0.f;
    for (int d = lane; d < MAXD; d += 64) {
        float v = hE[(size_t)i * MAXD + d];
        Hc[(size_t)i * MAXD + d] = v;
        s = fmaf(cnt[(size_t)i * MAXD + d], v, s);
    }
    #pragma unroll
    for (int off = 32; off; off >>= 1) s += __shfl_xor(s, off);
    if (lane == 0) ATSF(&deT[i], s / 1600.0f);   // epoch-0 data into slot 0
    if (i == 0) {
        // u16 pairs: slots 0..399 -> 0, slots 400..511 -> 0xFFFF (always pass).
        // Rewritten every launch (graph-replay safe).
        for (int k = lane; k < NFLAG / 2; k += 64)
            ATSU(&flags32[k], (k < NWAVE / 2) ? 0u : 0xFFFFFFFFu);
    }
}

#define ISSUE_DE() do { \
    asm volatile("global_load_dwordx4 %0, %1, off sc0 sc1" : "=v"(q0) : "v"(src + (lane*4         )) : "memory"); \
    asm volatile("global_load_dwordx4 %0, %1, off sc0 sc1" : "=v"(q1) : "v"(src + (lane*4 + 1*256)) : "memory"); \
    asm volatile("global_load_dwordx4 %0, %1, off sc0 sc1" : "=v"(q2) : "v"(src + (lane*4 + 2*256)) : "memory"); \
    asm volatile("global_load_dwordx4 %0, %1, off sc0 sc1" : "=v"(q3) : "v"(src + (lane*4 + 3*256)) : "memory"); \
    asm volatile("global_load_dwordx4 %0, %1, off sc0 sc1" : "=v"(q4) : "v"(src + (lane*4 + 4*256)) : "memory"); \
    asm volatile("global_load_dwordx4 %0, %1, off sc0 sc1" : "=v"(q5) : "v"(src + (lane*4 + 5*256)) : "memory"); \
    asm volatile("global_load_dword %0, %1, off sc0 sc1"   : "=v"(qx) : "v"(src + (1536 + lane   )) : "memory"); \
} while (0)

// one dwordx4/lane covers all 512 u16 flag slots (64 lanes x 4 u32 = 256 u32)
#define ISSUE_FLAGS() \
    asm volatile("global_load_dwordx4 %0, %1, off sc0 sc1" : "=v"(f1) : "v"(fp1) : "memory")

#define U16OK2(W) (unsigned)( (((W) & 0xFFFFu) >= tgt) & (((W) >> 16) >= tgt) )

__global__ __launch_bounds__(256, 1) void dmf_main(
        const float* __restrict__ x0, const float* __restrict__ L,
        const float* __restrict__ theta, const float* __restrict__ noise,
        float* __restrict__ out, const float* __restrict__ cnt,
        float* __restrict__ Hc, float* deT, u16* flags) {
    const int lane = threadIdx.x & 63;
    const int wv   = __builtin_amdgcn_readfirstlane(threadIdx.x >> 6);
    const int widx = blockIdx.x * WAVES + wv;   // 0..399
    const int base = widx * RPW;                // first row of this wave

    const float std_in = theta[0],  W_E = theta[1],  tau_E = theta[2], gamma_E = theta[3];
    const float W_I = theta[4],     tau_I = theta[5], I_0 = theta[6],  g = theta[7];
    const float g_EE = theta[8],    g_IE = theta[9], g_EI = theta[10];
    const float aE = theta[11], bE = theta[12], dEc = theta[13];
    const float aI = theta[14], bI = theta[15], dIc = theta[16];
    const float sdt = std_in * sqrtf(DT);

    // lane r (r < RPW) owns row base+r
    float E = 0.f, I = 0.f, cnt0 = 0.f;
    float* Hmy = Hc;
    if (lane < RPW) {
        const int i = base + lane;
        E = x0[i * 2 + 0];
        I = x0[i * 2 + 1];
        cnt0 = cnt[(size_t)i * MAXD];
        Hmy = Hc + (size_t)i * MAXD;
    }

    // delay-count weights in registers; d=0 excluded (added analytically)
    float creg[8][RPW];
    #pragma unroll
    for (int k = 0; k < 8; ++k) {
        const int d = lane + k * 64;
        #pragma unroll
        for (int r = 0; r < RPW; ++r)
            creg[k][r] = (d >= 1 && d < MAXD) ? cnt[(size_t)(base + r) * MAXD + d] : 0.f;
    }

    // L rows in registers: 4 rows x (6 float4 + 1 tail) = 100 VGPR
    float4 Lreg[RPW][6];
    float  Ltail[RPW];
    #pragma unroll
    for (int r = 0; r < RPW; ++r) {
        #pragma unroll
        for (int k = 0; k < 6; ++k)
            Lreg[r][k] = *(const float4*)&L[(size_t)(base + r) * NN + lane * 4 + k * 256];
        Ltail[r] = L[(size_t)(base + r) * NN + 1536 + lane];
    }

    const u32* fp1 = (const u32*)flags + lane * 4;   // covers all 512 u16 slots

    int h = 0;
    u32 e = 0;   // epochs completed (continuous across batches)

    uint4 f1;
    ISSUE_FLAGS();   // pre-issue for first gate check

    for (int b = 0; b < NBATCH; ++b) {
        float nE = 0.f, nI = 0.f;
        if (lane < RPW) {
            const int i = base + lane;
            nE = noise[((size_t)b * NN + i) * 2 + 0] * sdt;
            nI = noise[((size_t)b * NN + i) * 2 + 1] * sdt;
            ((float2*)out)[(size_t)b * TS * NN + i] = make_float2(E, I);
        }

        for (int t = 1; t < TS; ++t) {
            h = (h == 0) ? (MAXD - 1) : (h - 1);   // head where E_t will land

            // ---- 1. local history sum (d>=1) + reduce (overlaps in-flight
            //         flag load + prior off-path store acks)
            float s[RPW];
            #pragma unroll
            for (int r = 0; r < RPW; ++r) s[r] = 0.f;
            #pragma unroll
            for (int k = 0; k < 8; ++k) {
                const int d = lane + k * 64;
                if (d < MAXD) {
                    int hd = h + d; if (hd >= MAXD) hd -= MAXD;
                    #pragma unroll
                    for (int r = 0; r < RPW; ++r)
                        s[r] = fmaf(creg[k][r], Hc[(size_t)(base + r) * MAXD + hd], s[r]);
                }
            }
            #pragma unroll
            for (int off = 32; off; off >>= 1) {
                #pragma unroll
                for (int r = 0; r < RPW; ++r) s[r] += __shfl_xor(s[r], off);
            }
            float sv = s[0];
            #pragma unroll
            for (int r = 1; r < RPW; ++r) sv = (lane == r) ? s[r] : sv;

            // ---- 2. flag gate (first round pre-issued), sleep-backoff retries
            {
                const u32 tgt = e;
                for (;;) {
                    asm volatile("s_waitcnt vmcnt(0)" ::: "memory");
                    __builtin_amdgcn_sched_barrier(0);
                    const bool ok = U16OK2(f1.x) & U16OK2(f1.y)
                                  & U16OK2(f1.z) & U16OK2(f1.w);
                    if (__all(ok)) break;
                    __builtin_amdgcn_s_sleep(1);
                    ISSUE_FLAGS();
                }
            }

            // ---- 3. fetch exchange vector (gate + producer ack guarantee fresh)
            const float* src = deT + (size_t)(e & 1) * NN;
            float4 q0, q1, q2, q3, q4, q5;
            float  qx;
            ISSUE_DE();
            asm volatile("s_waitcnt vmcnt(0)" ::: "memory");
            __builtin_amdgcn_sched_barrier(0);

            // ---- 4. matvec entirely from registers
            float p[RPW];
            #pragma unroll
            for (int r = 0; r < RPW; ++r) {
                float acc = 0.f;
                acc = fmaf(Lreg[r][0].x, q0.x, acc); acc = fmaf(Lreg[r][0].y, q0.y, acc);
                acc = fmaf(Lreg[r][0].z, q0.z, acc); acc = fmaf(Lreg[r][0].w, q0.w, acc);
                acc = fmaf(Lreg[r][1].x, q1.x, acc); acc = fmaf(Lreg[r][1].y, q1.y, acc);
                acc = fmaf(Lreg[r][1].z, q1.z, acc); acc = fmaf(Lreg[r][1].w, q1.w, acc);
                acc = fmaf(Lreg[r][2].x, q2.x, acc); acc = fmaf(Lreg[r][2].y, q2.y, acc);
                acc = fmaf(Lreg[r][2].z, q2.z, acc); acc = fmaf(Lreg[r][2].w, q2.w, acc);
                acc = fmaf(Lreg[r][3].x, q3.x, acc); acc = fmaf(Lreg[r][3].y, q3.y, acc);
                acc = fmaf(Lreg[r][3].z, q3.z, acc); acc = fmaf(Lreg[r][3].w, q3.w, acc);
                acc = fmaf(Lreg[r][4].x, q4.x, acc); acc = fmaf(Lreg[r][4].y, q4.y, acc);
                acc = fmaf(Lreg[r][4].z, q4.z, acc); acc = fmaf(Lreg[r][4].w, q4.w, acc);
                acc = fmaf(Lreg[r][5].x, q5.x, acc); acc = fmaf(Lreg[r][5].y, q5.y, acc);
                acc = fmaf(Lreg[r][5].z, q5.z, acc); acc = fmaf(Lreg[r][5].w, q5.w, acc);
                acc = fmaf(Ltail[r], qx, acc);
                p[r] = acc;
            }
            #pragma unroll
            for (int off = 32; off; off >>= 1) {
                #pragma unroll
                for (int r = 0; r < RPW; ++r) p[r] += __shfl_xor(p[r], off);
            }
            float pv = p[0];
            #pragma unroll
            for (int r = 1; r < RPW; ++r) pv = (lane == r) ? p[r] : pv;

            // ---- 5. update; publish with r8-PROVEN sequence:
            //         dE store -> vmcnt(0) ack -> flag. Never remove the ack.
            float2 xi;
            if (lane < RPW) {
                const float IE = W_E * I_0 + g_EE * E + g * pv - g_IE * I;
                const float II = W_I * I_0 + g_EI * E - I;
                const float RE = h_tf_dev(aE, bE, dEc, IE);
                const float RI = h_tf_dev(aI, bI, dIc, II);
                const float dEd = -E / tau_E + (1.0f - E) * gamma_E * RE;
                const float dId = -I / tau_I + RI;
                E = E + DT * dEd + nE;
                I = I + DT * dId + nI;
                ATSF(&deT[(size_t)((e + 1) & 1) * NN + base + lane],
                     (sv + cnt0 * E) * (1.0f / 1600.0f));
                xi = make_float2(E, I);
            }
            // only the dE store is outstanding here -> cheap LLC ack
            asm volatile("s_waitcnt vmcnt(0)" ::: "memory");
            __builtin_amdgcn_sched_barrier(0);
            if (lane == 0) ATSU16(&flags[widx], (u16)(e + 1));
            // off-critical-path stores (drained by next step's gate)
            if (lane < RPW) {
                Hmy[h] = E;
                ((float2*)out)[(size_t)(b * TS + t) * NN + base + lane] = xi;
            }
            ISSUE_FLAGS();   // pre-issue next step's first gate round
            ++e;
        }
    }

    // ---- finals: x_f then hE_f (logical order from circular buffer)
    const size_t xo2 = (size_t)NBATCH * TS * NN;   // float2 index of x_f
    if (lane < RPW)
        ((float2*)out)[xo2 + base + lane] = make_float2(E, I);
    const size_t ho = 2 * xo2 + 2 * NN;            // float offset of hE_f
    #pragma unroll
    for (int k = 0; k < 8; ++k) {
        const int d = lane + k * 64;
        if (d < MAXD) {
            int hd = h + d; if (hd >= MAXD) hd -= MAXD;
            #pragma unroll
            for (int r = 0; r < RPW; ++r)
                out[ho + (size_t)(base + r) * MAXD + d] =
                    Hc[(size_t)(base + r) * MAXD + hd];
        }
    }
}

extern "C" void kernel_launch(void* const* d_in, const int* in_sizes, int n_in,
                              void* d_out, int out_size, void* d_ws, size_t ws_size,
                              hipStream_t stream) {
    const float* x0     = (const float*)d_in[0];
    const float* hE     = (const float*)d_in[1];
    const float* L      = (const float*)d_in[2];
    const float* theta  = (const float*)d_in[3];
    const float* noise  = (const float*)d_in[4];
    const int*   delays = (const int*)d_in[5];
    float* out = (float*)d_out;

    float* ws  = (float*)d_ws;
    float* cnt = ws;
    float* Hc  = ws + 800000;
    float* deT = ws + 1600000;
    u32*   flags32 = (u32*)(ws + 1603200);

    cnt_kernel<<<NN, 256, 0, stream>>>(delays, cnt);
    init_kernel<<<NN, 64, 0, stream>>>(hE, cnt, Hc, deT, flags32);
    dmf_main<<<GBLK, 256, 0, stream>>>(x0, L, theta, noise, out, cnt, Hc, deT,
                                       (u16*)flags32);
}

// Round 13
// 5522.143 us; speedup vs baseline: 2.7834x; 2.7834x over previous
//
#include <hip/hip_runtime.h>
#include <math.h>

#define NN 1600
#define MAXD 500
#define TS 500
#define NBATCH 4
#define GBLK 100
#define WAVES 4
#define NWAVE (GBLK * WAVES)   // 400 waves
#define RPW 4                  // rows per wave; 400*4 = 1600
#define NFLAG 512
#define DT 0.05f

typedef unsigned int u32;

// ---------------- workspace layout (floats) ----------------
// cnt   : [0      , 800000)   N*MAXD delay-count weights
// Hc    : [800000 , 1600000)  circular history, head h (logical d -> (h+d)%MAXD)
// dEbuf : [1600000, 1603200)  double-buffered delayed_E (2 * N)
// flags : float offset 1603200, NFLAG u32 dense (slots >= NWAVE preset to pass)

#define ATSF(p,v)  __hip_atomic_store((p), (v), __ATOMIC_RELAXED, __HIP_MEMORY_SCOPE_AGENT)
#define ATSU(p,v)  __hip_atomic_store((p), (v), __ATOMIC_RELAXED, __HIP_MEMORY_SCOPE_AGENT)

__device__ __forceinline__ float h_tf_dev(float a, float b, float d, float c) {
    float u   = a * c - b;
    float num = 1e-5f + fabsf(u);
    float den = 1e-5f * d + fabsf(1.0f - expf(-d * u));
    return num / (den + 1e-8f);
}

__global__ void cnt_kernel(const int* __restrict__ delays, float* __restrict__ cnt) {
    __shared__ int hist[MAXD];
    const int i = blockIdx.x;
    for (int d = threadIdx.x; d < MAXD; d += blockDim.x) hist[d] = 0;
    __syncthreads();
    const int* row = delays + (size_t)i * NN;
    for (int j = threadIdx.x; j < NN; j += blockDim.x) atomicAdd(&hist[row[j]], 1);
    __syncthreads();
    for (int d = threadIdx.x; d < MAXD; d += blockDim.x)
        cnt[(size_t)i * MAXD + d] = (float)hist[d];
}

__global__ void init_kernel(const float* __restrict__ hE, const float* __restrict__ cnt,
                            float* __restrict__ Hc, float* deT, u32* flags) {
    const int i = blockIdx.x;     // one wave per row
    const int lane = threadIdx.x; // 64 threads
    float s = 0.f;
    for (int d = lane; d < MAXD; d += 64) {
        float v = hE[(size_t)i * MAXD + d];
        Hc[(size_t)i * MAXD + d] = v;
        s = fmaf(cnt[(size_t)i * MAXD + d], v, s);
    }
    #pragma unroll
    for (int off = 32; off; off >>= 1) s += __shfl_xor(s, off);
    if (lane == 0) ATSF(&deT[i], s / 1600.0f);   // epoch-0 data into slot 0
    if (i == 0) {
        // re-init every launch (graph-replay safe)
        for (int k = lane; k < NFLAG; k += 64)
            ATSU(&flags[k], (k < NWAVE) ? 0u : 0x7FFFFFFFu);
    }
}

#define ISSUE_DE() do { \
    asm volatile("global_load_dwordx4 %0, %1, off sc0 sc1" : "=v"(q0) : "v"(src + (lane*4         )) : "memory"); \
    asm volatile("global_load_dwordx4 %0, %1, off sc0 sc1" : "=v"(q1) : "v"(src + (lane*4 + 1*256)) : "memory"); \
    asm volatile("global_load_dwordx4 %0, %1, off sc0 sc1" : "=v"(q2) : "v"(src + (lane*4 + 2*256)) : "memory"); \
    asm volatile("global_load_dwordx4 %0, %1, off sc0 sc1" : "=v"(q3) : "v"(src + (lane*4 + 3*256)) : "memory"); \
    asm volatile("global_load_dwordx4 %0, %1, off sc0 sc1" : "=v"(q4) : "v"(src + (lane*4 + 4*256)) : "memory"); \
    asm volatile("global_load_dwordx4 %0, %1, off sc0 sc1" : "=v"(q5) : "v"(src + (lane*4 + 5*256)) : "memory"); \
    asm volatile("global_load_dword %0, %1, off sc0 sc1"   : "=v"(qx) : "v"(src + (1536 + lane   )) : "memory"); \
} while (0)

__global__ __launch_bounds__(256, 1) void dmf_main(
        const float* __restrict__ x0, const float* __restrict__ L,
        const float* __restrict__ theta, const float* __restrict__ noise,
        float* __restrict__ out, const float* __restrict__ cnt,
        float* __restrict__ Hc, float* deT, u32* flags) {
    const int lane = threadIdx.x & 63;
    const int wv   = __builtin_amdgcn_readfirstlane(threadIdx.x >> 6);
    const int widx = blockIdx.x * WAVES + wv;   // 0..399
    const int base = widx * RPW;                // first row of this wave

    const float std_in = theta[0],  W_E = theta[1],  tau_E = theta[2], gamma_E = theta[3];
    const float W_I = theta[4],     tau_I = theta[5], I_0 = theta[6],  g = theta[7];
    const float g_EE = theta[8],    g_IE = theta[9], g_EI = theta[10];
    const float aE = theta[11], bE = theta[12], dEc = theta[13];
    const float aI = theta[14], bI = theta[15], dIc = theta[16];
    const float sdt = std_in * sqrtf(DT);

    // lane r (r < RPW) owns row base+r
    float E = 0.f, I = 0.f, cnt0 = 0.f;
    float* Hmy = Hc;
    if (lane < RPW) {
        const int i = base + lane;
        E = x0[i * 2 + 0];
        I = x0[i * 2 + 1];
        cnt0 = cnt[(size_t)i * MAXD];
        Hmy = Hc + (size_t)i * MAXD;
    }

    // delay-count weights in registers; d=0 excluded (added analytically)
    float creg[8][RPW];
    #pragma unroll
    for (int k = 0; k < 8; ++k) {
        const int d = lane + k * 64;
        #pragma unroll
        for (int r = 0; r < RPW; ++r)
            creg[k][r] = (d >= 1 && d < MAXD) ? cnt[(size_t)(base + r) * MAXD + d] : 0.f;
    }

    // L rows fully in registers: 4 rows x (6 float4 + 1 tail) = 100 VGPR
    float4 Lreg[RPW][6];
    float  Ltail[RPW];
    #pragma unroll
    for (int r = 0; r < RPW; ++r) {
        #pragma unroll
        for (int k = 0; k < 6; ++k)
            Lreg[r][k] = *(const float4*)&L[(size_t)(base + r) * NN + lane * 4 + k * 256];
        Ltail[r] = L[(size_t)(base + r) * NN + 1536 + lane];
    }

    const u32* fp1 = flags + lane * 4;         // covers 0..255
    const u32* fp2 = flags + 256 + lane * 4;   // covers 256..511 (>=400 always pass)

    int h = 0;
    u32 e = 0;   // epochs completed (continuous across batches)

    for (int b = 0; b < NBATCH; ++b) {
        float nE = 0.f, nI = 0.f;
        if (lane < RPW) {
            const int i = base + lane;
            nE = noise[((size_t)b * NN + i) * 2 + 0] * sdt;
            nI = noise[((size_t)b * NN + i) * 2 + 1] * sdt;
            ((float2*)out)[(size_t)b * TS * NN + i] = make_float2(E, I);
        }

        for (int t = 1; t < TS; ++t) {
            h = (h == 0) ? (MAXD - 1) : (h - 1);   // head where E_t will land

            // ---- 1. local history sum (d>=1) + reduce (no remote deps)
            float s[RPW];
            #pragma unroll
            for (int r = 0; r < RPW; ++r) s[r] = 0.f;
            #pragma unroll
            for (int k = 0; k < 8; ++k) {
                const int d = lane + k * 64;
                if (d < MAXD) {
                    int hd = h + d; if (hd >= MAXD) hd -= MAXD;
                    #pragma unroll
                    for (int r = 0; r < RPW; ++r)
                        s[r] = fmaf(creg[k][r], Hc[(size_t)(base + r) * MAXD + hd], s[r]);
                }
            }
            #pragma unroll
            for (int off = 32; off; off >>= 1) {
                #pragma unroll
                for (int r = 0; r < RPW; ++r) s[r] += __shfl_xor(s[r], off);
            }
            float sv = s[0];
            #pragma unroll
            for (int r = 1; r < RPW; ++r) sv = (lane == r) ? s[r] : sv;

            // ---- 2. poll per-wave flags (2 dwordx4 = all 512 slots)
            {
                const u32 tgt = e;
                for (;;) {
                    uint4 f1, f2;
                    asm volatile("global_load_dwordx4 %0, %1, off sc0 sc1"
                                 : "=v"(f1) : "v"(fp1) : "memory");
                    asm volatile("global_load_dwordx4 %0, %1, off sc0 sc1"
                                 : "=v"(f2) : "v"(fp2) : "memory");
                    asm volatile("s_waitcnt vmcnt(0)" ::: "memory");
                    __builtin_amdgcn_sched_barrier(0);
                    const bool ok = (f1.x >= tgt) & (f1.y >= tgt) & (f1.z >= tgt) & (f1.w >= tgt)
                                  & (f2.x >= tgt) & (f2.y >= tgt) & (f2.z >= tgt) & (f2.w >= tgt);
                    if (__all(ok)) break;
                    __builtin_amdgcn_s_sleep(1);
                }
            }

            // ---- 3. fetch exchange vector (flags guarantee freshness)
            const float* src = deT + (size_t)(e & 1) * NN;
            float4 q0, q1, q2, q3, q4, q5;
            float  qx;
            ISSUE_DE();
            asm volatile("s_waitcnt vmcnt(0)" ::: "memory");
            __builtin_amdgcn_sched_barrier(0);

            // ---- 4. matvec entirely from registers
            float p[RPW];
            #pragma unroll
            for (int r = 0; r < RPW; ++r) {
                float acc = 0.f;
                acc = fmaf(Lreg[r][0].x, q0.x, acc); acc = fmaf(Lreg[r][0].y, q0.y, acc);
                acc = fmaf(Lreg[r][0].z, q0.z, acc); acc = fmaf(Lreg[r][0].w, q0.w, acc);
                acc = fmaf(Lreg[r][1].x, q1.x, acc); acc = fmaf(Lreg[r][1].y, q1.y, acc);
                acc = fmaf(Lreg[r][1].z, q1.z, acc); acc = fmaf(Lreg[r][1].w, q1.w, acc);
                acc = fmaf(Lreg[r][2].x, q2.x, acc); acc = fmaf(Lreg[r][2].y, q2.y, acc);
                acc = fmaf(Lreg[r][2].z, q2.z, acc); acc = fmaf(Lreg[r][2].w, q2.w, acc);
                acc = fmaf(Lreg[r][3].x, q3.x, acc); acc = fmaf(Lreg[r][3].y, q3.y, acc);
                acc = fmaf(Lreg[r][3].z, q3.z, acc); acc = fmaf(Lreg[r][3].w, q3.w, acc);
                acc = fmaf(Lreg[r][4].x, q4.x, acc); acc = fmaf(Lreg[r][4].y, q4.y, acc);
                acc = fmaf(Lreg[r][4].z, q4.z, acc); acc = fmaf(Lreg[r][4].w, q4.w, acc);
                acc = fmaf(Lreg[r][5].x, q5.x, acc); acc = fmaf(Lreg[r][5].y, q5.y, acc);
                acc = fmaf(Lreg[r][5].z, q5.z, acc); acc = fmaf(Lreg[r][5].w, q5.w, acc);
                acc = fmaf(Ltail[r], qx, acc);
                p[r] = acc;
            }
            #pragma unroll
            for (int off = 32; off; off >>= 1) {
                #pragma unroll
                for (int r = 0; r < RPW; ++r) p[r] += __shfl_xor(p[r], off);
            }
            float pv = p[0];
            #pragma unroll
            for (int r = 1; r < RPW; ++r) pv = (lane == r) ? p[r] : pv;

            // ---- 5. update; publish dE FIRST, flag, then off-path stores
            float2 xi;
            if (lane < RPW) {
                const float IE = W_E * I_0 + g_EE * E + g * pv - g_IE * I;
                const float II = W_I * I_0 + g_EI * E - I;
                const float RE = h_tf_dev(aE, bE, dEc, IE);
                const float RI = h_tf_dev(aI, bI, dIc, II);
                const float dEd = -E / tau_E + (1.0f - E) * gamma_E * RE;
                const float dId = -I / tau_I + RI;
                E = E + DT * dEd + nE;
                I = I + DT * dId + nI;
                ATSF(&deT[(size_t)((e + 1) & 1) * NN + base + lane],
                     (sv + cnt0 * E) * (1.0f / 1600.0f));
                xi = make_float2(E, I);
            }
            // only the dE store is outstanding here -> cheap LLC ack
            asm volatile("s_waitcnt vmcnt(0)" ::: "memory");
            __builtin_amdgcn_sched_barrier(0);
            if (lane == 0) ATSU(&flags[widx], e + 1);
            // off-critical-path stores (drained by next step's poll)
            if (lane < RPW) {
                Hmy[h] = E;
                ((float2*)out)[(size_t)(b * TS + t) * NN + base + lane] = xi;
            }
            ++e;
        }
    }

    // ---- finals: x_f then hE_f (logical order from circular buffer)
    const size_t xo2 = (size_t)NBATCH * TS * NN;   // float2 index of x_f
    if (lane < RPW)
        ((float2*)out)[xo2 + base + lane] = make_float2(E, I);
    const size_t ho = 2 * xo2 + 2 * NN;            // float offset of hE_f
    #pragma unroll
    for (int k = 0; k < 8; ++k) {
        const int d = lane + k * 64;
        if (d < MAXD) {
            int hd = h + d; if (hd >= MAXD) hd -= MAXD;
            #pragma unroll
            for (int r = 0; r < RPW; ++r)
                out[ho + (size_t)(base + r) * MAXD + d] =
                    Hc[(size_t)(base + r) * MAXD + hd];
        }
    }
}

extern "C" void kernel_launch(void* const* d_in, const int* in_sizes, int n_in,
                              void* d_out, int out_size, void* d_ws, size_t ws_size,
                              hipStream_t stream) {
    const float* x0     = (const float*)d_in[0];
    const float* hE     = (const float*)d_in[1];
    const float* L      = (const float*)d_in[2];
    const float* theta  = (const float*)d_in[3];
    const float* noise  = (const float*)d_in[4];
    const int*   delays = (const int*)d_in[5];
    float* out = (float*)d_out;

    float* ws  = (float*)d_ws;
    float* cnt = ws;
    float* Hc  = ws + 800000;
    float* deT = ws + 1600000;
    u32*   flags = (u32*)(ws + 1603200);

    cnt_kernel<<<NN, 256, 0, stream>>>(delays, cnt);
    init_kernel<<<NN, 64, 0, stream>>>(hE, cnt, Hc, deT, flags);
    dmf_main<<<GBLK, 256, 0, stream>>>(x0, L, theta, noise, out, cnt, Hc, deT, flags);
}